// Round 1
// baseline (422.847 us; speedup 1.0000x reference)
//
#include <hip/hip_runtime.h>

// apply 2x2 gate to qubit axis TARGET=5 of state (2,)*24 + (4,), fp32.
// Target-axis stride S = 2^(23-TARGET) * BATCH = 2^18 * 4 = 2^20 elements.
// Flat: i = hi*(2S) + bit*S + lo,  hi in [0,32), lo in [0,S).
//
// Memory-bound: 256 MiB in + 256 MiB out. Vectorized float4, one thread per
// 4-element lo-chunk, computes both output halves of the pair.

constexpr unsigned S = 1u << 20;          // target-axis stride (elements)
constexpr unsigned VEC_PAIRS = 1u << 23;  // (2^26 total elems / 2 halves / 4 per float4)
constexpr unsigned LO_VEC = S / 4;        // 2^18 float4 chunks per hi-block

__global__ __launch_bounds__(256) void qubit_gate_kernel(
    const float* __restrict__ state,
    const float* __restrict__ pauli,
    float* __restrict__ out)
{
    const unsigned idx = blockIdx.x * blockDim.x + threadIdx.x;  // [0, 2^23)

    // wave-uniform broadcast loads, L1-resident
    const float p00 = pauli[0];
    const float p01 = pauli[1];
    const float p10 = pauli[2];
    const float p11 = pauli[3];

    const unsigned lo = (idx & (LO_VEC - 1)) << 2;  // element offset within hi-block
    const unsigned hi = idx >> 18;                  // [0, 32)
    const unsigned base = hi * (2 * S) + lo;        // max < 2^26, fits u32

    const float4 s0 = *reinterpret_cast<const float4*>(state + base);
    const float4 s1 = *reinterpret_cast<const float4*>(state + base + S);

    float4 o0, o1;
    o0.x = p00 * s0.x + p01 * s1.x;
    o0.y = p00 * s0.y + p01 * s1.y;
    o0.z = p00 * s0.z + p01 * s1.z;
    o0.w = p00 * s0.w + p01 * s1.w;
    o1.x = p10 * s0.x + p11 * s1.x;
    o1.y = p10 * s0.y + p11 * s1.y;
    o1.z = p10 * s0.z + p11 * s1.z;
    o1.w = p10 * s0.w + p11 * s1.w;

    *reinterpret_cast<float4*>(out + base)     = o0;
    *reinterpret_cast<float4*>(out + base + S) = o1;
}

extern "C" void kernel_launch(void* const* d_in, const int* in_sizes, int n_in,
                              void* d_out, int out_size, void* d_ws, size_t ws_size,
                              hipStream_t stream)
{
    const float* state = (const float*)d_in[0];
    const float* pauli = (const float*)d_in[1];
    float* out = (float*)d_out;

    const unsigned block = 256;
    const unsigned grid = VEC_PAIRS / block;  // 32768 blocks
    qubit_gate_kernel<<<grid, block, 0, stream>>>(state, pauli, out);
}